// Round 5
// baseline (36.586 us; speedup 1.0000x reference)
//
#include <hip/hip_runtime.h>
#include <stdint.h>

// RBF layer: out[b,r] = exp(-0.5 * sum_d ((x[b,d]-c[r,d])^2 / s[r,d]^2)),
// x = l2_normalize(inputs).  Expanded to one bf16 GEMM with K=1664 (zero-padded):
//   A_cat[b] = [ x^2 (784) | x (784) | 1, 0..0 ]
//   B_cat[r] = [ w (784)   | -2*c*w (784) | t3, 0..0 ],  w = 1/s^2, t3 = sum c^2 w
//   out = exp(-0.5 * A_cat · B_cat^T)
// R4 postmortem: GEMM is feed-BW-bound (~5.7 TB/s effective); TLP/chain changes were
// neutral.  R5: 64x64 tiles halve operand traffic (109 -> 54.5 MB).  128 blocks x
// 8 waves = 4 quadrants x 2-way K-split; pairwise LDS reduce + exp epilogue.

typedef unsigned short u16;
typedef u16   u16x8  __attribute__((ext_vector_type(8)));
typedef u16   u16x4  __attribute__((ext_vector_type(4)));
typedef __bf16 bf16x8 __attribute__((ext_vector_type(8)));
typedef float  f32x4  __attribute__((ext_vector_type(4)));

#define NB 2048
#define NR 256
#define ND 784
#define KC 1664   // 784 + 784 + 96 zero tail
#define KHALF 832 // per-wave K slice = 26 steps of 32
#define NSTEP 26
#define PF 5      // register prefetch depth (K-steps)

__device__ __forceinline__ u16 f2bf(float f) {
    union { float f; uint32_t u; } v; v.f = f;
    uint32_t r = v.u + 0x7fffu + ((v.u >> 16) & 1u);  // RNE
    return (u16)(r >> 16);
}

// ---------------- prep: build bf16 operand panels (unchanged from R4) ----------------
__global__ __launch_bounds__(256) void prep_kernel(
        const float* __restrict__ inputs, const float* __restrict__ centers,
        const float* __restrict__ sigmas, u16* __restrict__ Acat, u16* __restrict__ Bcat)
{
    const int w    = threadIdx.x >> 6;
    const int lane = threadIdx.x & 63;
    const int blk  = blockIdx.x;
    if (blk < 512) {
        const int b = blk * 4 + w;
        const float4* src = (const float4*)(inputs + (size_t)b * ND);
        float4 v0 = src[lane];
        float4 v1 = src[lane + 64];
        float4 v2 = src[lane + 128];
        float4 v3 = make_float4(0.f, 0.f, 0.f, 0.f);
        if (lane < 4) v3 = src[lane + 192];           // 784 = 4*(64+64+64+4)
        float ss = v0.x*v0.x + v0.y*v0.y + v0.z*v0.z + v0.w*v0.w
                 + v1.x*v1.x + v1.y*v1.y + v1.z*v1.z + v1.w*v1.w
                 + v2.x*v2.x + v2.y*v2.y + v2.z*v2.z + v2.w*v2.w
                 + v3.x*v3.x + v3.y*v3.y + v3.z*v3.z + v3.w*v3.w;
        #pragma unroll
        for (int m = 32; m; m >>= 1) ss += __shfl_xor(ss, m);
        const float inv = rsqrtf(fmaxf(ss, 1e-12f));
        u16* rowA = Acat + (size_t)b * KC;
        auto wrA = [&](int col, float4 v) {
            float x0 = v.x*inv, x1 = v.y*inv, x2 = v.z*inv, x3 = v.w*inv;
            u16x4 q2 = { f2bf(x0*x0), f2bf(x1*x1), f2bf(x2*x2), f2bf(x3*x3) };
            u16x4 q1 = { f2bf(x0),    f2bf(x1),    f2bf(x2),    f2bf(x3)    };
            *(u16x4*)(rowA + col)      = q2;
            *(u16x4*)(rowA + ND + col) = q1;
        };
        wrA(4*lane, v0);
        wrA(4*(lane+64), v1);
        wrA(4*(lane+128), v2);
        if (lane < 4) wrA(4*(lane+192), v3);
        if (lane < 24) {                               // tail cols [1568,1664)
            u16x4 t = {0,0,0,0};
            if (lane == 0) t.x = 0x3F80;               // bf16 1.0
            *(u16x4*)(rowA + 2*ND + 4*lane) = t;
        }
    } else {
        const int r = (blk - 512) * 4 + w;
        const float4* cp = (const float4*)(centers + (size_t)r * ND);
        const float4* sp = (const float4*)(sigmas  + (size_t)r * ND);
        u16* rowB = Bcat + (size_t)r * KC;
        float t3 = 0.f;
        auto wrB = [&](int col, float4 c, float4 s) {
            float w0 = 1.f/(s.x*s.x), w1 = 1.f/(s.y*s.y), w2 = 1.f/(s.z*s.z), w3 = 1.f/(s.w*s.w);
            float c0 = c.x*w0, c1 = c.y*w1, c2 = c.z*w2, c3 = c.w*w3;
            t3 += c.x*c0 + c.y*c1 + c.z*c2 + c.w*c3;
            u16x4 qw = { f2bf(w0), f2bf(w1), f2bf(w2), f2bf(w3) };
            u16x4 qm = { f2bf(-2.f*c0), f2bf(-2.f*c1), f2bf(-2.f*c2), f2bf(-2.f*c3) };
            *(u16x4*)(rowB + col)      = qw;
            *(u16x4*)(rowB + ND + col) = qm;
        };
        wrB(4*lane,       cp[lane],     sp[lane]);
        wrB(4*(lane+64),  cp[lane+64],  sp[lane+64]);
        wrB(4*(lane+128), cp[lane+128], sp[lane+128]);
        if (lane < 4) wrB(4*(lane+192), cp[lane+192], sp[lane+192]);
        #pragma unroll
        for (int m = 32; m; m >>= 1) t3 += __shfl_xor(t3, m);
        if (lane < 24) {
            u16x4 t = {0,0,0,0};
            if (lane == 0) t.x = f2bf(t3);
            *(u16x4*)(rowB + 2*ND + 4*lane) = t;
        }
    }
}

// ---------------- GEMM: 128 blocks x 8 waves; 64x64 tile ----------------
// Wave w: quadrant q=w>>1 (32x32 at (qi,qj)), K-half kh=w&1 (26 steps of 32).
// Per-block operand traffic (64+64)*3328 B = 426 KB -> 54.5 MB total (half of R4).
// Odd waves dump partials to LDS (17 KB), even waves add + exp + store.
__global__ __launch_bounds__(512) void rbf_gemm(
        const u16* __restrict__ Acat, const u16* __restrict__ Bcat, float* __restrict__ out)
{
    const int w    = threadIdx.x >> 6;   // 0..7
    const int lane = threadIdx.x & 63;
    const int bid  = (int)blockIdx.x;
    const int xcd  = bid & 7;
    const int j    = bid >> 3;           // 0..15
    const int mt   = xcd * 4 + (j & 3);  // 0..31
    const int nt   = j >> 2;             // 0..3
    const int wm   = mt * 64, wn = nt * 64;

    const int q   = w >> 1;              // quadrant 0..3
    const int qi  = q >> 1, qj = q & 1;
    const int kh  = w & 1;               // K half
    const int r16 = lane & 15;
    const int ko  = (lane >> 4) * 8;
    const int kb  = kh * KHALF;

    const u16* a0p = Acat + (size_t)(wm + 32*qi + r16) * KC + kb + ko;
    const u16* a1p = a0p + 16 * KC;
    const u16* b0p = Bcat + (size_t)(wn + 32*qj + r16) * KC + kb + ko;
    const u16* b1p = b0p + 16 * KC;

    f32x4 acc00 = {0,0,0,0}, acc01 = {0,0,0,0}, acc10 = {0,0,0,0}, acc11 = {0,0,0,0};
    u16x8 a0[PF], a1[PF], b0[PF], b1[PF];

#define LDSET(J, KS) do { const int o_ = (KS) * 32;                           \
    a0[J] = *(const u16x8*)(a0p + o_); a1[J] = *(const u16x8*)(a1p + o_);     \
    b0[J] = *(const u16x8*)(b0p + o_); b1[J] = *(const u16x8*)(b1p + o_); } while (0)

#define MM(J) do {                                                                        \
    acc00 = __builtin_amdgcn_mfma_f32_16x16x32_bf16(__builtin_bit_cast(bf16x8, a0[J]),    \
                __builtin_bit_cast(bf16x8, b0[J]), acc00, 0, 0, 0);                       \
    acc01 = __builtin_amdgcn_mfma_f32_16x16x32_bf16(__builtin_bit_cast(bf16x8, a0[J]),    \
                __builtin_bit_cast(bf16x8, b1[J]), acc01, 0, 0, 0);                       \
    acc10 = __builtin_amdgcn_mfma_f32_16x16x32_bf16(__builtin_bit_cast(bf16x8, a1[J]),    \
                __builtin_bit_cast(bf16x8, b0[J]), acc10, 0, 0, 0);                       \
    acc11 = __builtin_amdgcn_mfma_f32_16x16x32_bf16(__builtin_bit_cast(bf16x8, a1[J]),    \
                __builtin_bit_cast(bf16x8, b1[J]), acc11, 0, 0, 0); } while (0)

    #pragma unroll
    for (int s = 0; s < PF; ++s) LDSET(s, s);
    #pragma unroll
    for (int s = 0; s < NSTEP; ++s) {       // fully unrolled: all indices static
        MM(s % PF);
        if (s + PF < NSTEP) LDSET(s % PF, s + PF);
    }

    // ---- pairwise K-reduce via LDS: odd waves write, even waves add + exp + store ----
    __shared__ float red[4 * 32 * 33];       // 4 quadrant slabs, padded stride 33
    const int hi4 = (lane >> 4) << 2;
    float* slab = red + q * (32 * 33);
    if (kh) {
#define DUMP(ACC, MO, NO)                                             \
        { _Pragma("unroll")                                           \
          for (int qq = 0; qq < 4; ++qq)                              \
              slab[((MO) + hi4 + qq) * 33 + (NO) + r16] = ACC[qq]; }
        DUMP(acc00, 0, 0)  DUMP(acc01, 0, 16)
        DUMP(acc10, 16, 0) DUMP(acc11, 16, 16)
#undef DUMP
    }
    __syncthreads();
    if (!kh) {
        const int row0 = wm + 32*qi + hi4;
        const int col0 = wn + 32*qj + r16;
#define FIN(ACC, MO, NO)                                                        \
        { float* o_ = out + (size_t)(row0 + (MO)) * NR + col0 + (NO);           \
          _Pragma("unroll")                                                     \
          for (int qq = 0; qq < 4; ++qq) {                                      \
              float s_ = ACC[qq] + slab[((MO) + hi4 + qq) * 33 + (NO) + r16];   \
              o_[qq * NR] = __expf(-0.5f * s_); } }
        FIN(acc00, 0, 0)  FIN(acc01, 0, 16)
        FIN(acc10, 16, 0) FIN(acc11, 16, 16)
#undef FIN
    }
#undef LDSET
#undef MM
}

extern "C" void kernel_launch(void* const* d_in, const int* in_sizes, int n_in,
                              void* d_out, int out_size, void* d_ws, size_t ws_size,
                              hipStream_t stream) {
    const float* inputs  = (const float*)d_in[0];
    const float* centers = (const float*)d_in[1];
    const float* sigmas  = (const float*)d_in[2];
    u16* Acat = (u16*)d_ws;                       // 2048*1664*2 = 6.8 MB
    u16* Bcat = Acat + (size_t)NB * KC;           // + 256*1664*2 = 0.85 MB
    prep_kernel<<<576, 256, 0, stream>>>(inputs, centers, sigmas, Acat, Bcat);
    rbf_gemm<<<128, 512, 0, stream>>>(Acat, Bcat, (float*)d_out);
}

// Round 6
// 27.638 us; speedup vs baseline: 1.3237x; 1.3237x over previous
//
#include <hip/hip_runtime.h>
#include <stdint.h>

// RBF layer: out[b,r] = exp(-0.5 * sum_d ((x[b,d]-c[r,d])^2 / s[r,d]^2)),
// x = l2_normalize(inputs).  bf16 GEMM, K=1664 zero-padded:
//   A_cat[b] = [ x^2 (784) | x (784) | 1, 0..0 ]
//   B_cat[r] = [ w (784)   | -2*c*w (784) | t3, 0..0 ],  w = 1/s^2, t3 = sum c^2 w
// Model (R1-R5): time ~ L3 traffic / 5.7 TB/s, valid only with all 256 CUs active.
// R6: 64x64 tiles (54.4 MB operands, vs R4's 109) x KS=2 across block PAIRS
// (disjoint K halves) = 256 blocks; f16 partials (2 MB) + reduce+exp kernel.

typedef unsigned short u16;
typedef u16      u16x8  __attribute__((ext_vector_type(8)));
typedef u16      u16x4  __attribute__((ext_vector_type(4)));
typedef __bf16   bf16x8 __attribute__((ext_vector_type(8)));
typedef float    f32x4  __attribute__((ext_vector_type(4)));
typedef _Float16 f16x8  __attribute__((ext_vector_type(8)));

#define NB 2048
#define NR 256
#define ND 784
#define KC 1664   // 784 + 784 + 96 zero tail
#define KHALF 832 // per-K-half slice = 26 steps of 32
#define NSTEP 26
#define PF 5      // register prefetch depth (K-steps)

__device__ __forceinline__ u16 f2bf(float f) {
    union { float f; uint32_t u; } v; v.f = f;
    uint32_t r = v.u + 0x7fffu + ((v.u >> 16) & 1u);  // RNE
    return (u16)(r >> 16);
}

// ---------------- prep: build bf16 operand panels (unchanged, verified R1-R5) --------
__global__ __launch_bounds__(256) void prep_kernel(
        const float* __restrict__ inputs, const float* __restrict__ centers,
        const float* __restrict__ sigmas, u16* __restrict__ Acat, u16* __restrict__ Bcat)
{
    const int w    = threadIdx.x >> 6;
    const int lane = threadIdx.x & 63;
    const int blk  = blockIdx.x;
    if (blk < 512) {
        const int b = blk * 4 + w;
        const float4* src = (const float4*)(inputs + (size_t)b * ND);
        float4 v0 = src[lane];
        float4 v1 = src[lane + 64];
        float4 v2 = src[lane + 128];
        float4 v3 = make_float4(0.f, 0.f, 0.f, 0.f);
        if (lane < 4) v3 = src[lane + 192];           // 784 = 4*(64+64+64+4)
        float ss = v0.x*v0.x + v0.y*v0.y + v0.z*v0.z + v0.w*v0.w
                 + v1.x*v1.x + v1.y*v1.y + v1.z*v1.z + v1.w*v1.w
                 + v2.x*v2.x + v2.y*v2.y + v2.z*v2.z + v2.w*v2.w
                 + v3.x*v3.x + v3.y*v3.y + v3.z*v3.z + v3.w*v3.w;
        #pragma unroll
        for (int m = 32; m; m >>= 1) ss += __shfl_xor(ss, m);
        const float inv = rsqrtf(fmaxf(ss, 1e-12f));
        u16* rowA = Acat + (size_t)b * KC;
        auto wrA = [&](int col, float4 v) {
            float x0 = v.x*inv, x1 = v.y*inv, x2 = v.z*inv, x3 = v.w*inv;
            u16x4 q2 = { f2bf(x0*x0), f2bf(x1*x1), f2bf(x2*x2), f2bf(x3*x3) };
            u16x4 q1 = { f2bf(x0),    f2bf(x1),    f2bf(x2),    f2bf(x3)    };
            *(u16x4*)(rowA + col)      = q2;
            *(u16x4*)(rowA + ND + col) = q1;
        };
        wrA(4*lane, v0);
        wrA(4*(lane+64), v1);
        wrA(4*(lane+128), v2);
        if (lane < 4) wrA(4*(lane+192), v3);
        if (lane < 24) {                               // tail cols [1568,1664)
            u16x4 t = {0,0,0,0};
            if (lane == 0) t.x = 0x3F80;               // bf16 1.0
            *(u16x4*)(rowA + 2*ND + 4*lane) = t;
        }
    } else {
        const int r = (blk - 512) * 4 + w;
        const float4* cp = (const float4*)(centers + (size_t)r * ND);
        const float4* sp = (const float4*)(sigmas  + (size_t)r * ND);
        u16* rowB = Bcat + (size_t)r * KC;
        float t3 = 0.f;
        auto wrB = [&](int col, float4 c, float4 s) {
            float w0 = 1.f/(s.x*s.x), w1 = 1.f/(s.y*s.y), w2 = 1.f/(s.z*s.z), w3 = 1.f/(s.w*s.w);
            float c0 = c.x*w0, c1 = c.y*w1, c2 = c.z*w2, c3 = c.w*w3;
            t3 += c.x*c0 + c.y*c1 + c.z*c2 + c.w*c3;
            u16x4 qw = { f2bf(w0), f2bf(w1), f2bf(w2), f2bf(w3) };
            u16x4 qm = { f2bf(-2.f*c0), f2bf(-2.f*c1), f2bf(-2.f*c2), f2bf(-2.f*c3) };
            *(u16x4*)(rowB + col)      = qw;
            *(u16x4*)(rowB + ND + col) = qm;
        };
        wrB(4*lane,       cp[lane],     sp[lane]);
        wrB(4*(lane+64),  cp[lane+64],  sp[lane+64]);
        wrB(4*(lane+128), cp[lane+128], sp[lane+128]);
        if (lane < 4) wrB(4*(lane+192), cp[lane+192], sp[lane+192]);
        #pragma unroll
        for (int m = 32; m; m >>= 1) t3 += __shfl_xor(t3, m);
        if (lane < 24) {
            u16x4 t = {0,0,0,0};
            if (lane == 0) t.x = f2bf(t3);
            *(u16x4*)(rowB + 2*ND + 4*lane) = t;
        }
    }
}

// ---------------- GEMM: 256 blocks x 4 waves; 64x64 tile; K-half per block ----------
// bid -> (mt 0..31, nt 0..3, kh 0..1); XCD x owns A rows [256x, 256x+256).
// Wave w = quadrant (w>>1, w&1) of the 64x64 tile; 26 K-steps, PF=5 pipeline.
// Writes f16 partial dist to P[kh] (no LDS, no barriers).
__global__ __launch_bounds__(256) void rbf_gemm(
        const u16* __restrict__ Acat, const u16* __restrict__ Bcat,
        _Float16* __restrict__ P)
{
    const int w    = threadIdx.x >> 6;   // 0..3 quadrant
    const int lane = threadIdx.x & 63;
    const int bid  = (int)blockIdx.x;
    const int xcd  = bid & 7;
    const int j    = bid >> 3;           // 0..31
    const int mt   = xcd * 4 + (j & 3);  // 0..31
    const int nt   = (j >> 2) & 3;       // 0..3
    const int kh   = j >> 4;             // 0..1
    const int wm   = mt * 64 + (w >> 1) * 32;
    const int wn   = nt * 64 + (w & 1) * 32;
    const int r16  = lane & 15;
    const int ko   = (lane >> 4) * 8;
    const int kb   = kh * KHALF;

    const u16* a0p = Acat + (size_t)(wm + r16) * KC + kb + ko;
    const u16* a1p = a0p + 16 * KC;
    const u16* b0p = Bcat + (size_t)(wn + r16) * KC + kb + ko;
    const u16* b1p = b0p + 16 * KC;

    f32x4 acc00 = {0,0,0,0}, acc01 = {0,0,0,0}, acc10 = {0,0,0,0}, acc11 = {0,0,0,0};
    u16x8 a0[PF], a1[PF], b0[PF], b1[PF];

#define LDSET(J, KS) do { const int o_ = (KS) * 32;                           \
    a0[J] = *(const u16x8*)(a0p + o_); a1[J] = *(const u16x8*)(a1p + o_);     \
    b0[J] = *(const u16x8*)(b0p + o_); b1[J] = *(const u16x8*)(b1p + o_); } while (0)

#define MM(J) do {                                                                        \
    acc00 = __builtin_amdgcn_mfma_f32_16x16x32_bf16(__builtin_bit_cast(bf16x8, a0[J]),    \
                __builtin_bit_cast(bf16x8, b0[J]), acc00, 0, 0, 0);                       \
    acc01 = __builtin_amdgcn_mfma_f32_16x16x32_bf16(__builtin_bit_cast(bf16x8, a0[J]),    \
                __builtin_bit_cast(bf16x8, b1[J]), acc01, 0, 0, 0);                       \
    acc10 = __builtin_amdgcn_mfma_f32_16x16x32_bf16(__builtin_bit_cast(bf16x8, a1[J]),    \
                __builtin_bit_cast(bf16x8, b0[J]), acc10, 0, 0, 0);                       \
    acc11 = __builtin_amdgcn_mfma_f32_16x16x32_bf16(__builtin_bit_cast(bf16x8, a1[J]),    \
                __builtin_bit_cast(bf16x8, b1[J]), acc11, 0, 0, 0); } while (0)

    #pragma unroll
    for (int s = 0; s < PF; ++s) LDSET(s, s);
    #pragma unroll
    for (int s = 0; s < NSTEP; ++s) {       // fully unrolled: all indices static
        MM(s % PF);
        if (s + PF < NSTEP) LDSET(s % PF, s + PF);
    }

    // f16 partial store; C/D layout (HW-verified): col=lane&15, row=(lane>>4)*4+reg
    _Float16* dst = P + (size_t)kh * NB * NR;
    const int hi4 = (lane >> 4) << 2;
#define STOREP(ACC, MO, NO) do {                                              \
    _Float16* o_ = dst + (size_t)(wm + (MO) + hi4) * NR + wn + (NO) + r16;    \
    o_[0]    = (_Float16)ACC[0];                                              \
    o_[NR]   = (_Float16)ACC[1];                                              \
    o_[2*NR] = (_Float16)ACC[2];                                              \
    o_[3*NR] = (_Float16)ACC[3]; } while (0)

    STOREP(acc00, 0, 0);  STOREP(acc01, 0, 16);
    STOREP(acc10, 16, 0); STOREP(acc11, 16, 16);
#undef LDSET
#undef MM
#undef STOREP
}

// ---------------- reduce: out = exp(-0.5*(P0+P1)), vectorized x8 ----------------
__global__ __launch_bounds__(256) void rbf_reduce(
        const _Float16* __restrict__ P, float* __restrict__ out)
{
    const int i = ((int)blockIdx.x * 256 + (int)threadIdx.x) * 8;  // 256 blocks cover 512K
    f16x8 p0 = *(const f16x8*)(P + i);
    f16x8 p1 = *(const f16x8*)(P + (size_t)NB * NR + i);
    f32x4 r0, r1;
    #pragma unroll
    for (int k = 0; k < 4; ++k) r0[k] = __expf(-0.5f * ((float)p0[k]     + (float)p1[k]));
    #pragma unroll
    for (int k = 0; k < 4; ++k) r1[k] = __expf(-0.5f * ((float)p0[4 + k] + (float)p1[4 + k]));
    *(f32x4*)(out + i)     = r0;
    *(f32x4*)(out + i + 4) = r1;
}

extern "C" void kernel_launch(void* const* d_in, const int* in_sizes, int n_in,
                              void* d_out, int out_size, void* d_ws, size_t ws_size,
                              hipStream_t stream) {
    const float* inputs  = (const float*)d_in[0];
    const float* centers = (const float*)d_in[1];
    const float* sigmas  = (const float*)d_in[2];
    u16* Acat = (u16*)d_ws;                        // 2048*1664*2 = 6.82 MB
    u16* Bcat = Acat + (size_t)NB * KC;            // + 256*1664*2 = 0.85 MB
    _Float16* P = (_Float16*)(Bcat + (size_t)NR * KC);  // + 2*2048*256*2 = 2 MB
    prep_kernel<<<576, 256, 0, stream>>>(inputs, centers, sigmas, Acat, Bcat);
    rbf_gemm<<<256, 256, 0, stream>>>(Acat, Bcat, P);
    rbf_reduce<<<256, 256, 0, stream>>>(P, (float*)d_out);
}

// Round 7
// 25.349 us; speedup vs baseline: 1.4433x; 1.0903x over previous
//
#include <hip/hip_runtime.h>
#include <stdint.h>

// RBF layer: out[b,r] = exp(-0.5 * sum_d ((x[b,d]-c[r,d])^2 / s[r,d]^2)),
// x = l2_normalize(inputs).  bf16 GEMM, K=1664 zero-padded:
//   A_cat[b] = [ x^2 (784) | x (784) | 1, 0..0 ]
//   B_cat[r] = [ w (784)   | -2*c*w (784) | t3, 0..0 ],  w = 1/s^2, t3 = sum c^2 w
// Model after R1-R6: total = fixed overhead (~5 us/launch + replay) + prep (~3 us)
// + gemm feed (aggregate ~16 TB/s with all CUs pulling).  R7: back to 2 launches
// with 64x32 tiles (81.8 MB, vs R4's 109 at same launch count): 256 blocks =
// 32 M-tiles x 8 N-tiles; 4 waves = 2 M-halves x 2 K-halves; LDS pairwise reduce.

typedef unsigned short u16;
typedef u16      u16x8  __attribute__((ext_vector_type(8)));
typedef u16      u16x4  __attribute__((ext_vector_type(4)));
typedef __bf16   bf16x8 __attribute__((ext_vector_type(8)));
typedef float    f32x4  __attribute__((ext_vector_type(4)));

#define NB 2048
#define NR 256
#define ND 784
#define KC 1664   // 784 + 784 + 96 zero tail
#define KHALF 832 // per-K-half slice = 26 steps of 32
#define NSTEP 26
#define PF 5      // register prefetch depth (K-steps)

__device__ __forceinline__ u16 f2bf(float f) {
    union { float f; uint32_t u; } v; v.f = f;
    uint32_t r = v.u + 0x7fffu + ((v.u >> 16) & 1u);  // RNE
    return (u16)(r >> 16);
}

// ---------------- prep: build bf16 operand panels (byte-identical since R4) ----------
__global__ __launch_bounds__(256) void prep_kernel(
        const float* __restrict__ inputs, const float* __restrict__ centers,
        const float* __restrict__ sigmas, u16* __restrict__ Acat, u16* __restrict__ Bcat)
{
    const int w    = threadIdx.x >> 6;
    const int lane = threadIdx.x & 63;
    const int blk  = blockIdx.x;
    if (blk < 512) {
        const int b = blk * 4 + w;
        const float4* src = (const float4*)(inputs + (size_t)b * ND);
        float4 v0 = src[lane];
        float4 v1 = src[lane + 64];
        float4 v2 = src[lane + 128];
        float4 v3 = make_float4(0.f, 0.f, 0.f, 0.f);
        if (lane < 4) v3 = src[lane + 192];           // 784 = 4*(64+64+64+4)
        float ss = v0.x*v0.x + v0.y*v0.y + v0.z*v0.z + v0.w*v0.w
                 + v1.x*v1.x + v1.y*v1.y + v1.z*v1.z + v1.w*v1.w
                 + v2.x*v2.x + v2.y*v2.y + v2.z*v2.z + v2.w*v2.w
                 + v3.x*v3.x + v3.y*v3.y + v3.z*v3.z + v3.w*v3.w;
        #pragma unroll
        for (int m = 32; m; m >>= 1) ss += __shfl_xor(ss, m);
        const float inv = rsqrtf(fmaxf(ss, 1e-12f));
        u16* rowA = Acat + (size_t)b * KC;
        auto wrA = [&](int col, float4 v) {
            float x0 = v.x*inv, x1 = v.y*inv, x2 = v.z*inv, x3 = v.w*inv;
            u16x4 q2 = { f2bf(x0*x0), f2bf(x1*x1), f2bf(x2*x2), f2bf(x3*x3) };
            u16x4 q1 = { f2bf(x0),    f2bf(x1),    f2bf(x2),    f2bf(x3)    };
            *(u16x4*)(rowA + col)      = q2;
            *(u16x4*)(rowA + ND + col) = q1;
        };
        wrA(4*lane, v0);
        wrA(4*(lane+64), v1);
        wrA(4*(lane+128), v2);
        if (lane < 4) wrA(4*(lane+192), v3);
        if (lane < 24) {                               // tail cols [1568,1664)
            u16x4 t = {0,0,0,0};
            if (lane == 0) t.x = 0x3F80;               // bf16 1.0
            *(u16x4*)(rowA + 2*ND + 4*lane) = t;
        }
    } else {
        const int r = (blk - 512) * 4 + w;
        const float4* cp = (const float4*)(centers + (size_t)r * ND);
        const float4* sp = (const float4*)(sigmas  + (size_t)r * ND);
        u16* rowB = Bcat + (size_t)r * KC;
        float t3 = 0.f;
        auto wrB = [&](int col, float4 c, float4 s) {
            float w0 = 1.f/(s.x*s.x), w1 = 1.f/(s.y*s.y), w2 = 1.f/(s.z*s.z), w3 = 1.f/(s.w*s.w);
            float c0 = c.x*w0, c1 = c.y*w1, c2 = c.z*w2, c3 = c.w*w3;
            t3 += c.x*c0 + c.y*c1 + c.z*c2 + c.w*c3;
            u16x4 qw = { f2bf(w0), f2bf(w1), f2bf(w2), f2bf(w3) };
            u16x4 qm = { f2bf(-2.f*c0), f2bf(-2.f*c1), f2bf(-2.f*c2), f2bf(-2.f*c3) };
            *(u16x4*)(rowB + col)      = qw;
            *(u16x4*)(rowB + ND + col) = qm;
        };
        wrB(4*lane,       cp[lane],     sp[lane]);
        wrB(4*(lane+64),  cp[lane+64],  sp[lane+64]);
        wrB(4*(lane+128), cp[lane+128], sp[lane+128]);
        if (lane < 4) wrB(4*(lane+192), cp[lane+192], sp[lane+192]);
        #pragma unroll
        for (int m = 32; m; m >>= 1) t3 += __shfl_xor(t3, m);
        if (lane < 24) {
            u16x4 t = {0,0,0,0};
            if (lane == 0) t.x = f2bf(t3);
            *(u16x4*)(rowB + 2*ND + 4*lane) = t;
        }
    }
}

// ---------------- GEMM: 256 blocks x 4 waves; 64x32 tile; intra-block K-split -------
// bid -> (mt 0..31, nt 0..7); XCD x owns A rows [256x, 256x+256).
// Wave w: M-half qm=w>>1 (32 rows), K-half kh=w&1 (26 steps of 32); PF=5 pipeline.
// kh=1 waves dump partials to LDS; kh=0 waves add + exp + store (R4-verified pattern).
__global__ __launch_bounds__(256) void rbf_gemm(
        const u16* __restrict__ Acat, const u16* __restrict__ Bcat,
        float* __restrict__ out)
{
    const int w    = threadIdx.x >> 6;   // 0..3
    const int lane = threadIdx.x & 63;
    const int bid  = (int)blockIdx.x;
    const int xcd  = bid & 7;
    const int j    = bid >> 3;           // 0..31
    const int mt   = xcd * 4 + (j & 3);  // 0..31
    const int nt   = j >> 2;             // 0..7
    const int qm   = w >> 1;             // M half
    const int kh   = w & 1;              // K half
    const int wm   = mt * 64 + qm * 32;
    const int wn   = nt * 32;
    const int r16  = lane & 15;
    const int ko   = (lane >> 4) * 8;
    const int kb   = kh * KHALF;

    const u16* a0p = Acat + (size_t)(wm + r16) * KC + kb + ko;
    const u16* a1p = a0p + 16 * KC;
    const u16* b0p = Bcat + (size_t)(wn + r16) * KC + kb + ko;
    const u16* b1p = b0p + 16 * KC;

    f32x4 acc00 = {0,0,0,0}, acc01 = {0,0,0,0}, acc10 = {0,0,0,0}, acc11 = {0,0,0,0};
    u16x8 a0[PF], a1[PF], b0[PF], b1[PF];

#define LDSET(J, KS) do { const int o_ = (KS) * 32;                           \
    a0[J] = *(const u16x8*)(a0p + o_); a1[J] = *(const u16x8*)(a1p + o_);     \
    b0[J] = *(const u16x8*)(b0p + o_); b1[J] = *(const u16x8*)(b1p + o_); } while (0)

#define MM(J) do {                                                                        \
    acc00 = __builtin_amdgcn_mfma_f32_16x16x32_bf16(__builtin_bit_cast(bf16x8, a0[J]),    \
                __builtin_bit_cast(bf16x8, b0[J]), acc00, 0, 0, 0);                       \
    acc01 = __builtin_amdgcn_mfma_f32_16x16x32_bf16(__builtin_bit_cast(bf16x8, a0[J]),    \
                __builtin_bit_cast(bf16x8, b1[J]), acc01, 0, 0, 0);                       \
    acc10 = __builtin_amdgcn_mfma_f32_16x16x32_bf16(__builtin_bit_cast(bf16x8, a1[J]),    \
                __builtin_bit_cast(bf16x8, b0[J]), acc10, 0, 0, 0);                       \
    acc11 = __builtin_amdgcn_mfma_f32_16x16x32_bf16(__builtin_bit_cast(bf16x8, a1[J]),    \
                __builtin_bit_cast(bf16x8, b1[J]), acc11, 0, 0, 0); } while (0)

    #pragma unroll
    for (int s = 0; s < PF; ++s) LDSET(s, s);
    #pragma unroll
    for (int s = 0; s < NSTEP; ++s) {       // fully unrolled: all indices static
        MM(s % PF);
        if (s + PF < NSTEP) LDSET(s % PF, s + PF);
    }

    // ---- pairwise K-reduce via LDS: kh=1 writes, kh=0 adds + exp + stores ----
    __shared__ float red[2 * 32 * 33];       // 2 M-half slabs, padded stride 33
    const int hi4 = (lane >> 4) << 2;
    float* slab = red + qm * (32 * 33);
    if (kh) {
#define DUMP(ACC, MO, NO)                                             \
        { _Pragma("unroll")                                           \
          for (int qq = 0; qq < 4; ++qq)                              \
              slab[((MO) + hi4 + qq) * 33 + (NO) + r16] = ACC[qq]; }
        DUMP(acc00, 0, 0)  DUMP(acc01, 0, 16)
        DUMP(acc10, 16, 0) DUMP(acc11, 16, 16)
#undef DUMP
    }
    __syncthreads();
    if (!kh) {
        const int row0 = wm + hi4;
        const int col0 = wn + r16;
#define FIN(ACC, MO, NO)                                                        \
        { float* o_ = out + (size_t)(row0 + (MO)) * NR + col0 + (NO);           \
          _Pragma("unroll")                                                     \
          for (int qq = 0; qq < 4; ++qq) {                                      \
              float s_ = ACC[qq] + slab[((MO) + hi4 + qq) * 33 + (NO) + r16];   \
              o_[qq * NR] = __expf(-0.5f * s_); } }
        FIN(acc00, 0, 0)  FIN(acc01, 0, 16)
        FIN(acc10, 16, 0) FIN(acc11, 16, 16)
#undef FIN
    }
#undef LDSET
#undef MM
}

extern "C" void kernel_launch(void* const* d_in, const int* in_sizes, int n_in,
                              void* d_out, int out_size, void* d_ws, size_t ws_size,
                              hipStream_t stream) {
    const float* inputs  = (const float*)d_in[0];
    const float* centers = (const float*)d_in[1];
    const float* sigmas  = (const float*)d_in[2];
    u16* Acat = (u16*)d_ws;                        // 2048*1664*2 = 6.82 MB
    u16* Bcat = Acat + (size_t)NB * KC;            // + 256*1664*2 = 0.85 MB
    prep_kernel<<<576, 256, 0, stream>>>(inputs, centers, sigmas, Acat, Bcat);
    rbf_gemm<<<256, 256, 0, stream>>>(Acat, Bcat, (float*)d_out);
}

// Round 8
// 18.681 us; speedup vs baseline: 1.9584x; 1.3569x over previous
//
#include <hip/hip_runtime.h>
#include <stdint.h>

// RBF layer: out[b,r] = exp(-0.5 * sum_d ((x[b,d]-c[r,d])^2 / s[r,d]^2)),
// x = l2_normalize(inputs).  INT8 GEMM with per-row max-scaling:
//   A_i8[b] = [ q2 = rint(x^2/s2_b) (832) | q1 = rint(x/s1_b) (832) ]
//   B_i8[r] = [ qw = rint(w/u_r)    (832) | qm = rint(-2cw/v_r) (832) ],  w = 1/s^2
//   dist[b,r] = s2_b*u_r*dot(q2,qw) + s1_b*v_r*dot(q1,qm) + t3_r  (t3 = sum c^2 w, f32)
// Model (R1-R7, 7/7 fit): gemm_time = LOADED bytes / ~9.8 TB/s (L1 line-fill bound),
// insensitive to TLP/PF/chain.  int8 halves loaded bytes: 107 MB -> 54.5 MB.

typedef char   i8x16 __attribute__((ext_vector_type(16)));
typedef int    i32x4 __attribute__((ext_vector_type(4)));
typedef float  f32x4 __attribute__((ext_vector_type(4)));

#define NB 2048
#define NR 256
#define ND 784
#define KR 1664   // row bytes: 2 panels x 832
#define KP 832    // panel: 784 data + 48 zero pad; 13 MFMA-K64 steps
#define NSTEP 13
#define PF 5
#define INV127 0.007874015748031496f

// ---------------- prep: build int8 panels + per-row scales ----------------
// blocks 0..511: 4 input rows each (1 wave/row).  blocks 512..575: 4 center rows each.
__global__ __launch_bounds__(256) void prep_kernel(
        const float* __restrict__ inputs, const float* __restrict__ centers,
        const float* __restrict__ sigmas, uint8_t* __restrict__ Acat,
        uint8_t* __restrict__ Bcat, float* __restrict__ SA1, float* __restrict__ SA2,
        float* __restrict__ SU, float* __restrict__ SV, float* __restrict__ ST)
{
    const int w    = threadIdx.x >> 6;
    const int lane = threadIdx.x & 63;
    const int blk  = blockIdx.x;
    if (blk < 512) {
        const int b = blk * 4 + w;
        const float4* src = (const float4*)(inputs + (size_t)b * ND);
        float4 v0 = src[lane];
        float4 v1 = src[lane + 64];
        float4 v2 = src[lane + 128];
        float4 v3 = make_float4(0.f, 0.f, 0.f, 0.f);
        if (lane < 4) v3 = src[lane + 192];            // 784 = 4*(64+64+64+4)
        float ss = v0.x*v0.x + v0.y*v0.y + v0.z*v0.z + v0.w*v0.w
                 + v1.x*v1.x + v1.y*v1.y + v1.z*v1.z + v1.w*v1.w
                 + v2.x*v2.x + v2.y*v2.y + v2.z*v2.z + v2.w*v2.w
                 + v3.x*v3.x + v3.y*v3.y + v3.z*v3.z + v3.w*v3.w;
        float mg = fmaxf(fmaxf(fmaxf(fabsf(v0.x), fabsf(v0.y)), fmaxf(fabsf(v0.z), fabsf(v0.w))),
                   fmaxf(fmaxf(fmaxf(fabsf(v1.x), fabsf(v1.y)), fmaxf(fabsf(v1.z), fabsf(v1.w))),
                   fmaxf(fmaxf(fmaxf(fabsf(v2.x), fabsf(v2.y)), fmaxf(fabsf(v2.z), fabsf(v2.w))),
                         fmaxf(fmaxf(fabsf(v3.x), fabsf(v3.y)), fmaxf(fabsf(v3.z), fabsf(v3.w))))));
        #pragma unroll
        for (int m = 32; m; m >>= 1) {
            ss += __shfl_xor(ss, m);
            mg  = fmaxf(mg, __shfl_xor(mg, m));
        }
        const float inv = rsqrtf(fmaxf(ss, 1e-12f));
        const float mx  = fmaxf(mg * inv, 1e-30f);     // max |x| over row
        const float r1  = 127.0f / mx;
        const float r2  = 127.0f / (mx * mx);
        uint8_t* rowA = Acat + (size_t)b * KR;
        auto pk = [&](float4 g, int col) {
            float x0 = g.x*inv, x1 = g.y*inv, x2 = g.z*inv, x3 = g.w*inv;
            int a0 = __float2int_rn(x0*x0*r2), a1 = __float2int_rn(x1*x1*r2);
            int a2 = __float2int_rn(x2*x2*r2), a3 = __float2int_rn(x3*x3*r2);
            int b0 = __float2int_rn(x0*r1),    b1 = __float2int_rn(x1*r1);
            int b2 = __float2int_rn(x2*r1),    b3 = __float2int_rn(x3*r1);
            uint32_t q2 = (a0&255) | ((a1&255)<<8) | ((a2&255)<<16) | ((a3&255)<<24);
            uint32_t q1 = (b0&255) | ((b1&255)<<8) | ((b2&255)<<16) | ((b3&255)<<24);
            *(uint32_t*)(rowA + col)      = q2;
            *(uint32_t*)(rowA + KP + col) = q1;
        };
        pk(v0, 4*lane);
        pk(v1, 4*(lane+64));
        pk(v2, 4*(lane+128));
        if (lane < 4) pk(v3, 4*(lane+192));
        if (lane < 12) {                               // zero pad cols [784,832) both panels
            *(uint32_t*)(rowA + ND + 4*lane)      = 0u;
            *(uint32_t*)(rowA + KP + ND + 4*lane) = 0u;
        }
        if (lane == 0) { SA1[b] = mx * INV127; SA2[b] = mx * mx * INV127; }
    } else {
        const int r = (blk - 512) * 4 + w;
        const float4* cp = (const float4*)(centers + (size_t)r * ND);
        const float4* sp = (const float4*)(sigmas  + (size_t)r * ND);
        float4 c0 = cp[lane],     s0 = sp[lane];
        float4 c1 = cp[lane+64],  s1 = sp[lane+64];
        float4 c2 = cp[lane+128], s2 = sp[lane+128];
        float4 c3 = make_float4(0,0,0,0), s3 = make_float4(1,1,1,1);
        const bool v3ok = lane < 4;
        if (v3ok) { c3 = cp[lane+192]; s3 = sp[lane+192]; }
        float4 w0, w1, w2, w3;
        w0.x=1.f/(s0.x*s0.x); w0.y=1.f/(s0.y*s0.y); w0.z=1.f/(s0.z*s0.z); w0.w=1.f/(s0.w*s0.w);
        w1.x=1.f/(s1.x*s1.x); w1.y=1.f/(s1.y*s1.y); w1.z=1.f/(s1.z*s1.z); w1.w=1.f/(s1.w*s1.w);
        w2.x=1.f/(s2.x*s2.x); w2.y=1.f/(s2.y*s2.y); w2.z=1.f/(s2.z*s2.z); w2.w=1.f/(s2.w*s2.w);
        w3.x=1.f/(s3.x*s3.x); w3.y=1.f/(s3.y*s3.y); w3.z=1.f/(s3.z*s3.z); w3.w=1.f/(s3.w*s3.w);
        if (!v3ok) { w3 = make_float4(0,0,0,0); }      // neutral for max/sum
        float t3 = c0.x*c0.x*w0.x + c0.y*c0.y*w0.y + c0.z*c0.z*w0.z + c0.w*c0.w*w0.w
                 + c1.x*c1.x*w1.x + c1.y*c1.y*w1.y + c1.z*c1.z*w1.z + c1.w*c1.w*w1.w
                 + c2.x*c2.x*w2.x + c2.y*c2.y*w2.y + c2.z*c2.z*w2.z + c2.w*c2.w*w2.w
                 + c3.x*c3.x*w3.x + c3.y*c3.y*w3.y + c3.z*c3.z*w3.z + c3.w*c3.w*w3.w;
        float mw = fmaxf(fmaxf(w0.x, w0.y), fmaxf(w0.z, w0.w));
        mw = fmaxf(mw, fmaxf(fmaxf(w1.x, w1.y), fmaxf(w1.z, w1.w)));
        mw = fmaxf(mw, fmaxf(fmaxf(w2.x, w2.y), fmaxf(w2.z, w2.w)));
        mw = fmaxf(mw, fmaxf(fmaxf(w3.x, w3.y), fmaxf(w3.z, w3.w)));
        float mm = fmaxf(fmaxf(fabsf(2.f*c0.x*w0.x), fabsf(2.f*c0.y*w0.y)),
                         fmaxf(fabsf(2.f*c0.z*w0.z), fabsf(2.f*c0.w*w0.w)));
        mm = fmaxf(mm, fmaxf(fmaxf(fabsf(2.f*c1.x*w1.x), fabsf(2.f*c1.y*w1.y)),
                             fmaxf(fabsf(2.f*c1.z*w1.z), fabsf(2.f*c1.w*w1.w))));
        mm = fmaxf(mm, fmaxf(fmaxf(fabsf(2.f*c2.x*w2.x), fabsf(2.f*c2.y*w2.y)),
                             fmaxf(fabsf(2.f*c2.z*w2.z), fabsf(2.f*c2.w*w2.w))));
        mm = fmaxf(mm, fmaxf(fmaxf(fabsf(2.f*c3.x*w3.x), fabsf(2.f*c3.y*w3.y)),
                             fmaxf(fabsf(2.f*c3.z*w3.z), fabsf(2.f*c3.w*w3.w))));
        #pragma unroll
        for (int m = 32; m; m >>= 1) {
            t3 += __shfl_xor(t3, m);
            mw  = fmaxf(mw, __shfl_xor(mw, m));
            mm  = fmaxf(mm, __shfl_xor(mm, m));
        }
        mw = fmaxf(mw, 1e-30f); mm = fmaxf(mm, 1e-30f);
        const float ru = 127.0f / mw, rv = 127.0f / mm;
        uint8_t* rowB = Bcat + (size_t)r * KR;
        auto pkB = [&](float4 c, float4 ww, int col) {
            int a0 = __float2int_rn(ww.x*ru), a1 = __float2int_rn(ww.y*ru);
            int a2 = __float2int_rn(ww.z*ru), a3 = __float2int_rn(ww.w*ru);
            int b0 = __float2int_rn(-2.f*c.x*ww.x*rv), b1 = __float2int_rn(-2.f*c.y*ww.y*rv);
            int b2 = __float2int_rn(-2.f*c.z*ww.z*rv), b3 = __float2int_rn(-2.f*c.w*ww.w*rv);
            uint32_t qw = (a0&255) | ((a1&255)<<8) | ((a2&255)<<16) | ((a3&255)<<24);
            uint32_t qm = (b0&255) | ((b1&255)<<8) | ((b2&255)<<16) | ((b3&255)<<24);
            *(uint32_t*)(rowB + col)      = qw;
            *(uint32_t*)(rowB + KP + col) = qm;
        };
        pkB(c0, w0, 4*lane);
        pkB(c1, w1, 4*(lane+64));
        pkB(c2, w2, 4*(lane+128));
        if (v3ok) pkB(c3, w3, 4*(lane+192));
        if (lane < 12) {
            *(uint32_t*)(rowB + ND + 4*lane)      = 0u;
            *(uint32_t*)(rowB + KP + ND + 4*lane) = 0u;
        }
        if (lane == 0) { SU[r] = mw * INV127; SV[r] = mm * INV127; ST[r] = t3; }
    }
}

// ---------------- GEMM: 256 blocks x 4 waves; 64x32 tile; panel split across waves ----
// Wave w: M-half qm=w>>1, panel kh=w&1 (kh=0: x^2*w -> d1; kh=1: x*(-2cw) -> d2).
// 13 steps of K=64 i8 per wave, PF=5.  Loaded/block = 213 KB -> 54.5 MB chip.
// kh=1 dumps i32 acc to LDS; kh=0 combines with scales + t3, exp, stores.
__global__ __launch_bounds__(256) void rbf_gemm(
        const uint8_t* __restrict__ Acat, const uint8_t* __restrict__ Bcat,
        const float* __restrict__ SA1, const float* __restrict__ SA2,
        const float* __restrict__ SU, const float* __restrict__ SV,
        const float* __restrict__ ST, float* __restrict__ out)
{
    const int w    = threadIdx.x >> 6;   // 0..3
    const int lane = threadIdx.x & 63;
    const int bid  = (int)blockIdx.x;
    const int xcd  = bid & 7;
    const int j    = bid >> 3;           // 0..31
    const int mt   = xcd * 4 + (j & 3);  // 0..31
    const int nt   = j >> 2;             // 0..7
    const int qm   = w >> 1;             // M half
    const int kh   = w & 1;              // panel
    const int wm   = mt * 64 + qm * 32;
    const int wn   = nt * 32;
    const int r16  = lane & 15;
    const int ko   = (lane >> 4) * 16;   // byte offset within K=64 step

    const uint8_t* a0p = Acat + (size_t)(wm + r16) * KR + kh * KP + ko;
    const uint8_t* a1p = a0p + 16 * KR;
    const uint8_t* b0p = Bcat + (size_t)(wn + r16) * KR + kh * KP + ko;
    const uint8_t* b1p = b0p + 16 * KR;

    i32x4 acc00 = {0,0,0,0}, acc01 = {0,0,0,0}, acc10 = {0,0,0,0}, acc11 = {0,0,0,0};
    i32x4 a0[PF], a1[PF], b0[PF], b1[PF];

#define LDSET(J, KS) do { const int o_ = (KS) * 64;                           \
    a0[J] = *(const i32x4*)(a0p + o_); a1[J] = *(const i32x4*)(a1p + o_);     \
    b0[J] = *(const i32x4*)(b0p + o_); b1[J] = *(const i32x4*)(b1p + o_); } while (0)

#define MM(J) do {                                                                 \
    acc00 = __builtin_amdgcn_mfma_i32_16x16x64_i8(a0[J], b0[J], acc00, 0, 0, 0);   \
    acc01 = __builtin_amdgcn_mfma_i32_16x16x64_i8(a0[J], b1[J], acc01, 0, 0, 0);   \
    acc10 = __builtin_amdgcn_mfma_i32_16x16x64_i8(a1[J], b0[J], acc10, 0, 0, 0);   \
    acc11 = __builtin_amdgcn_mfma_i32_16x16x64_i8(a1[J], b1[J], acc11, 0, 0, 0); } while (0)

    #pragma unroll
    for (int s = 0; s < PF; ++s) LDSET(s, s);
    #pragma unroll
    for (int s = 0; s < NSTEP; ++s) {       // fully unrolled: all indices static
        MM(s % PF);
        if (s + PF < NSTEP) LDSET(s % PF, s + PF);
    }

    // ---- combine: kh=1 writes d2 to LDS; kh=0 dequants d1+d2 + t3, exp, stores ----
    __shared__ int red[2 * 32 * 33];         // 2 M-half slabs, padded stride 33
    const int hi4 = (lane >> 4) << 2;
    int* slab = red + qm * (32 * 33);
    if (kh) {
#define DUMP(ACC, MO, NO)                                             \
        { _Pragma("unroll")                                           \
          for (int qq = 0; qq < 4; ++qq)                              \
              slab[((MO) + hi4 + qq) * 33 + (NO) + r16] = ACC[qq]; }
        DUMP(acc00, 0, 0)  DUMP(acc01, 0, 16)
        DUMP(acc10, 16, 0) DUMP(acc11, 16, 16)
#undef DUMP
    }
    __syncthreads();
    if (!kh) {
        const int c0 = wn + r16, c1 = wn + 16 + r16;
        const float u0 = SU[c0], v0 = SV[c0], t0 = ST[c0];
        const float u1 = SU[c1], v1 = SV[c1], t1 = ST[c1];
#define FIN(ACC, MO, NO, UU, VV, TT)                                              \
        { const int rw0 = wm + (MO) + hi4;                                        \
          float* o_ = out + (size_t)rw0 * NR + wn + (NO) + r16;                   \
          _Pragma("unroll")                                                       \
          for (int qq = 0; qq < 4; ++qq) {                                        \
              const int rr = rw0 + qq;                                            \
              const float d2 = (float)slab[((MO) + hi4 + qq) * 33 + (NO) + r16];  \
              const float dist = SA2[rr] * (UU) * (float)ACC[qq]                  \
                               + SA1[rr] * (VV) * d2 + (TT);                      \
              o_[qq * NR] = __expf(-0.5f * dist); } }
        FIN(acc00, 0, 0, u0, v0, t0)   FIN(acc01, 0, 16, u1, v1, t1)
        FIN(acc10, 16, 0, u0, v0, t0)  FIN(acc11, 16, 16, u1, v1, t1)
#undef FIN
    }
#undef LDSET
#undef MM
}

extern "C" void kernel_launch(void* const* d_in, const int* in_sizes, int n_in,
                              void* d_out, int out_size, void* d_ws, size_t ws_size,
                              hipStream_t stream) {
    const float* inputs  = (const float*)d_in[0];
    const float* centers = (const float*)d_in[1];
    const float* sigmas  = (const float*)d_in[2];
    uint8_t* Acat = (uint8_t*)d_ws;                    // 2048*1664 = 3.41 MB
    uint8_t* Bcat = Acat + (size_t)NB * KR;            // + 256*1664 = 0.43 MB
    float*   scal = (float*)(Bcat + (size_t)NR * KR);  // + ~19 KB of scales
    float* SA1 = scal;            // [2048]
    float* SA2 = scal + 2048;     // [2048]
    float* SU  = scal + 4096;     // [256]
    float* SV  = scal + 4352;     // [256]
    float* ST  = scal + 4608;     // [256]
    prep_kernel<<<576, 256, 0, stream>>>(inputs, centers, sigmas, Acat, Bcat,
                                         SA1, SA2, SU, SV, ST);
    rbf_gemm<<<256, 256, 0, stream>>>(Acat, Bcat, SA1, SA2, SU, SV, ST, (float*)d_out);
}

// Round 9
// 15.829 us; speedup vs baseline: 2.3113x; 1.1802x over previous
//
#include <hip/hip_runtime.h>
#include <stdint.h>

// RBF layer: out[b,r] = exp(-0.5 * sum_d ((x[b,d]-c[r,d])^2 / s[r,d]^2)),
// x = l2_normalize(inputs).  INT8 GEMM with per-row max-scaling:
//   A_i8[b] = [ q2 = rint(x^2/s2_b) | q1 = rint(x/s1_b) ]          (2 panels x 832 B)
//   B_i8[r] = [ qw = rint(w/u_r)    | qm = rint(-2cw/v_r) ],  w = 1/s^2
//   dist = s2*u*dot(q2,qw) + s1*v*dot(q1,qm) + t3,   t3 = sum c^2 w  (f32 exact)
// Model (R1-R8, 8/8 fit): gemm_time = LOADED bytes / ~9.8 TB/s, schedule-insensitive.
// R9: constant-sigma fast path.  If a sigma row is constant (w_rd == W_r for all d,
// exact max==min check), term1 = W_r * sum(x^2) = W_r EXACTLY (x l2-normalized).
// Gemm blocks whose 32 columns are all flagged load ONLY the q1/qm panel (27.3 MB
// instead of 54.5), K-split 7/6 steps across the kh wave pair.  Per-block fallback
// to the full R8 path keeps generality.

typedef int    i32x4 __attribute__((ext_vector_type(4)));
typedef float  f32x4 __attribute__((ext_vector_type(4)));

#define NB 2048
#define NR 256
#define ND 784
#define KR 1664   // row bytes: 2 panels x 832
#define KP 832    // panel: 784 data + 48 zero pad; 13 MFMA-K64 steps
#define PF 5
#define INV127 0.007874015748031496f

// ---------------- prep: build int8 panels + per-row scales + const-sigma flags -------
__global__ __launch_bounds__(256) void prep_kernel(
        const float* __restrict__ inputs, const float* __restrict__ centers,
        const float* __restrict__ sigmas, uint8_t* __restrict__ Acat,
        uint8_t* __restrict__ Bcat, float* __restrict__ SA1, float* __restrict__ SA2,
        float* __restrict__ SU, float* __restrict__ SV, float* __restrict__ ST,
        float* __restrict__ WR, uint32_t* __restrict__ FLG)
{
    const int w    = threadIdx.x >> 6;
    const int lane = threadIdx.x & 63;
    const int blk  = blockIdx.x;
    if (blk < 512) {
        const int b = blk * 4 + w;
        const float4* src = (const float4*)(inputs + (size_t)b * ND);
        float4 v0 = src[lane];
        float4 v1 = src[lane + 64];
        float4 v2 = src[lane + 128];
        float4 v3 = make_float4(0.f, 0.f, 0.f, 0.f);
        if (lane < 4) v3 = src[lane + 192];            // 784 = 4*(64+64+64+4)
        float ss = v0.x*v0.x + v0.y*v0.y + v0.z*v0.z + v0.w*v0.w
                 + v1.x*v1.x + v1.y*v1.y + v1.z*v1.z + v1.w*v1.w
                 + v2.x*v2.x + v2.y*v2.y + v2.z*v2.z + v2.w*v2.w
                 + v3.x*v3.x + v3.y*v3.y + v3.z*v3.z + v3.w*v3.w;
        float mg = fmaxf(fmaxf(fmaxf(fabsf(v0.x), fabsf(v0.y)), fmaxf(fabsf(v0.z), fabsf(v0.w))),
                   fmaxf(fmaxf(fmaxf(fabsf(v1.x), fabsf(v1.y)), fmaxf(fabsf(v1.z), fabsf(v1.w))),
                   fmaxf(fmaxf(fmaxf(fabsf(v2.x), fabsf(v2.y)), fmaxf(fabsf(v2.z), fabsf(v2.w))),
                         fmaxf(fmaxf(fabsf(v3.x), fabsf(v3.y)), fmaxf(fabsf(v3.z), fabsf(v3.w))))));
        #pragma unroll
        for (int m = 32; m; m >>= 1) {
            ss += __shfl_xor(ss, m);
            mg  = fmaxf(mg, __shfl_xor(mg, m));
        }
        const float inv = rsqrtf(fmaxf(ss, 1e-12f));
        const float mx  = fmaxf(mg * inv, 1e-30f);     // max |x| over row
        const float r1  = 127.0f / mx;
        const float r2  = 127.0f / (mx * mx);
        uint8_t* rowA = Acat + (size_t)b * KR;
        auto pk = [&](float4 g, int col) {
            float x0 = g.x*inv, x1 = g.y*inv, x2 = g.z*inv, x3 = g.w*inv;
            int a0 = __float2int_rn(x0*x0*r2), a1 = __float2int_rn(x1*x1*r2);
            int a2 = __float2int_rn(x2*x2*r2), a3 = __float2int_rn(x3*x3*r2);
            int b0 = __float2int_rn(x0*r1),    b1 = __float2int_rn(x1*r1);
            int b2 = __float2int_rn(x2*r1),    b3 = __float2int_rn(x3*r1);
            uint32_t q2 = (a0&255) | ((a1&255)<<8) | ((a2&255)<<16) | ((a3&255)<<24);
            uint32_t q1 = (b0&255) | ((b1&255)<<8) | ((b2&255)<<16) | ((b3&255)<<24);
            *(uint32_t*)(rowA + col)      = q2;
            *(uint32_t*)(rowA + KP + col) = q1;
        };
        pk(v0, 4*lane);
        pk(v1, 4*(lane+64));
        pk(v2, 4*(lane+128));
        if (lane < 4) pk(v3, 4*(lane+192));
        if (lane < 12) {                               // zero pad cols [784,832) both panels
            *(uint32_t*)(rowA + ND + 4*lane)      = 0u;
            *(uint32_t*)(rowA + KP + ND + 4*lane) = 0u;
        }
        if (lane == 0) { SA1[b] = mx * INV127; SA2[b] = mx * mx * INV127; }
    } else {
        const int r = (blk - 512) * 4 + w;
        const float4* cp = (const float4*)(centers + (size_t)r * ND);
        const float4* sp = (const float4*)(sigmas  + (size_t)r * ND);
        float4 c0 = cp[lane],     s0 = sp[lane];
        float4 c1 = cp[lane+64],  s1 = sp[lane+64];
        float4 c2 = cp[lane+128], s2 = sp[lane+128];
        float4 c3 = make_float4(0,0,0,0), s3 = make_float4(1,1,1,1);
        const bool v3ok = lane < 4;
        if (v3ok) { c3 = cp[lane+192]; s3 = sp[lane+192]; }
        float4 w0, w1, w2, w3;
        w0.x=1.f/(s0.x*s0.x); w0.y=1.f/(s0.y*s0.y); w0.z=1.f/(s0.z*s0.z); w0.w=1.f/(s0.w*s0.w);
        w1.x=1.f/(s1.x*s1.x); w1.y=1.f/(s1.y*s1.y); w1.z=1.f/(s1.z*s1.z); w1.w=1.f/(s1.w*s1.w);
        w2.x=1.f/(s2.x*s2.x); w2.y=1.f/(s2.y*s2.y); w2.z=1.f/(s2.z*s2.z); w2.w=1.f/(s2.w*s2.w);
        w3.x=1.f/(s3.x*s3.x); w3.y=1.f/(s3.y*s3.y); w3.z=1.f/(s3.z*s3.z); w3.w=1.f/(s3.w*s3.w);
        // row-constancy: min/max over REAL elements only
        float wmn = fminf(fminf(fminf(w0.x,w0.y), fminf(w0.z,w0.w)),
                    fminf(fminf(fminf(w1.x,w1.y), fminf(w1.z,w1.w)),
                          fminf(fminf(w2.x,w2.y), fminf(w2.z,w2.w))));
        float wmx = fmaxf(fmaxf(fmaxf(w0.x,w0.y), fmaxf(w0.z,w0.w)),
                    fmaxf(fmaxf(fmaxf(w1.x,w1.y), fmaxf(w1.z,w1.w)),
                          fmaxf(fmaxf(w2.x,w2.y), fmaxf(w2.z,w2.w))));
        if (v3ok) {
            wmn = fminf(wmn, fminf(fminf(w3.x,w3.y), fminf(w3.z,w3.w)));
            wmx = fmaxf(wmx, fmaxf(fmaxf(w3.x,w3.y), fmaxf(w3.z,w3.w)));
        }
        if (!v3ok) { w3 = make_float4(0,0,0,0); }      // neutral for t3 / mm sums below
        float t3 = c0.x*c0.x*w0.x + c0.y*c0.y*w0.y + c0.z*c0.z*w0.z + c0.w*c0.w*w0.w
                 + c1.x*c1.x*w1.x + c1.y*c1.y*w1.y + c1.z*c1.z*w1.z + c1.w*c1.w*w1.w
                 + c2.x*c2.x*w2.x + c2.y*c2.y*w2.y + c2.z*c2.z*w2.z + c2.w*c2.w*w2.w
                 + c3.x*c3.x*w3.x + c3.y*c3.y*w3.y + c3.z*c3.z*w3.z + c3.w*c3.w*w3.w;
        float mw = fmaxf(fmaxf(w0.x, w0.y), fmaxf(w0.z, w0.w));
        mw = fmaxf(mw, fmaxf(fmaxf(w1.x, w1.y), fmaxf(w1.z, w1.w)));
        mw = fmaxf(mw, fmaxf(fmaxf(w2.x, w2.y), fmaxf(w2.z, w2.w)));
        mw = fmaxf(mw, fmaxf(fmaxf(w3.x, w3.y), fmaxf(w3.z, w3.w)));
        float mm = fmaxf(fmaxf(fabsf(2.f*c0.x*w0.x), fabsf(2.f*c0.y*w0.y)),
                         fmaxf(fabsf(2.f*c0.z*w0.z), fabsf(2.f*c0.w*w0.w)));
        mm = fmaxf(mm, fmaxf(fmaxf(fabsf(2.f*c1.x*w1.x), fabsf(2.f*c1.y*w1.y)),
                             fmaxf(fabsf(2.f*c1.z*w1.z), fabsf(2.f*c1.w*w1.w))));
        mm = fmaxf(mm, fmaxf(fmaxf(fabsf(2.f*c2.x*w2.x), fabsf(2.f*c2.y*w2.y)),
                             fmaxf(fabsf(2.f*c2.z*w2.z), fabsf(2.f*c2.w*w2.w))));
        mm = fmaxf(mm, fmaxf(fmaxf(fabsf(2.f*c3.x*w3.x), fabsf(2.f*c3.y*w3.y)),
                             fmaxf(fabsf(2.f*c3.z*w3.z), fabsf(2.f*c3.w*w3.w))));
        #pragma unroll
        for (int m = 32; m; m >>= 1) {
            t3 += __shfl_xor(t3, m);
            mw  = fmaxf(mw, __shfl_xor(mw, m));
            mm  = fmaxf(mm, __shfl_xor(mm, m));
            wmn = fminf(wmn, __shfl_xor(wmn, m));
            wmx = fmaxf(wmx, __shfl_xor(wmx, m));
        }
        mw = fmaxf(mw, 1e-30f); mm = fmaxf(mm, 1e-30f);
        const float ru = 127.0f / mw, rv = 127.0f / mm;
        uint8_t* rowB = Bcat + (size_t)r * KR;
        auto pkB = [&](float4 c, float4 ww, int col) {
            int a0 = __float2int_rn(ww.x*ru), a1 = __float2int_rn(ww.y*ru);
            int a2 = __float2int_rn(ww.z*ru), a3 = __float2int_rn(ww.w*ru);
            int b0 = __float2int_rn(-2.f*c.x*ww.x*rv), b1 = __float2int_rn(-2.f*c.y*ww.y*rv);
            int b2 = __float2int_rn(-2.f*c.z*ww.z*rv), b3 = __float2int_rn(-2.f*c.w*ww.w*rv);
            uint32_t qw = (a0&255) | ((a1&255)<<8) | ((a2&255)<<16) | ((a3&255)<<24);
            uint32_t qm = (b0&255) | ((b1&255)<<8) | ((b2&255)<<16) | ((b3&255)<<24);
            *(uint32_t*)(rowB + col)      = qw;
            *(uint32_t*)(rowB + KP + col) = qm;
        };
        pkB(c0, w0, 4*lane);
        pkB(c1, w1, 4*(lane+64));
        pkB(c2, w2, 4*(lane+128));
        if (v3ok) pkB(c3, w3, 4*(lane+192));
        if (lane < 12) {
            *(uint32_t*)(rowB + ND + 4*lane)      = 0u;
            *(uint32_t*)(rowB + KP + ND + 4*lane) = 0u;
        }
        if (lane == 0) {
            SU[r] = mw * INV127; SV[r] = mm * INV127; ST[r] = t3;
            WR[r] = wmn; FLG[r] = (wmn == wmx) ? 1u : 0u;
        }
    }
}

// ---- K-chain: NST compile-time steps of K=64 starting at step BASE; PF pipeline ----
#define LDSET(J, KS) do { const int o_ = (KS) * 64;                           \
    a0[J] = *(const i32x4*)(a0p + o_); a1[J] = *(const i32x4*)(a1p + o_);     \
    b0[J] = *(const i32x4*)(b0p + o_); b1[J] = *(const i32x4*)(b1p + o_); } while (0)
#define MM(J) do {                                                                 \
    acc00 = __builtin_amdgcn_mfma_i32_16x16x64_i8(a0[J], b0[J], acc00, 0, 0, 0);   \
    acc01 = __builtin_amdgcn_mfma_i32_16x16x64_i8(a0[J], b1[J], acc01, 0, 0, 0);   \
    acc10 = __builtin_amdgcn_mfma_i32_16x16x64_i8(a1[J], b0[J], acc10, 0, 0, 0);   \
    acc11 = __builtin_amdgcn_mfma_i32_16x16x64_i8(a1[J], b1[J], acc11, 0, 0, 0); } while (0)

template<int NST, int BASE>
__device__ __forceinline__ void chain_i8(
        const uint8_t* __restrict__ a0p, const uint8_t* __restrict__ a1p,
        const uint8_t* __restrict__ b0p, const uint8_t* __restrict__ b1p,
        i32x4& acc00, i32x4& acc01, i32x4& acc10, i32x4& acc11)
{
    i32x4 a0[PF], a1[PF], b0[PF], b1[PF];
    constexpr int PRE = (PF < NST) ? PF : NST;
    #pragma unroll
    for (int s = 0; s < PRE; ++s) LDSET(s, BASE + s);
    #pragma unroll
    for (int s = 0; s < NST; ++s) {          // fully unrolled: all indices static
        MM(s % PF);
        if (s + PF < NST) LDSET(s % PF, BASE + s + PF);
    }
}
#undef LDSET
#undef MM

// ---------------- GEMM: 256 blocks x 4 waves; 64x32 tile ----------------
// Fast path (all 32 columns sigma-const): q1/qm panel only, K-split 7/6 across kh.
// Slow path: R8 two-panel split.  kh=1 dumps i32 acc to LDS; kh=0 combines + exp.
__global__ __launch_bounds__(256) void rbf_gemm(
        const uint8_t* __restrict__ Acat, const uint8_t* __restrict__ Bcat,
        const float* __restrict__ SA1, const float* __restrict__ SA2,
        const float* __restrict__ SU, const float* __restrict__ SV,
        const float* __restrict__ ST, const float* __restrict__ WR,
        const uint32_t* __restrict__ FLG, float* __restrict__ out)
{
    const int w    = threadIdx.x >> 6;   // 0..3
    const int lane = threadIdx.x & 63;
    const int bid  = (int)blockIdx.x;
    const int xcd  = bid & 7;
    const int j    = bid >> 3;           // 0..31
    const int mt   = xcd * 4 + (j & 3);  // 0..31
    const int nt   = j >> 2;             // 0..7
    const int qm   = w >> 1;             // M half
    const int kh   = w & 1;              // panel (slow) / K-chunk (fast)
    const int wm   = mt * 64 + qm * 32;
    const int wn   = nt * 32;
    const int r16  = lane & 15;
    const int ko   = (lane >> 4) * 16;   // byte offset within K=64 step

    uint32_t fv = 1u;
    if (lane < 32) fv = FLG[wn + lane];
    const bool fast = __all(fv != 0u);   // block-uniform (wn same for all waves)

    i32x4 acc00 = {0,0,0,0}, acc01 = {0,0,0,0}, acc10 = {0,0,0,0}, acc11 = {0,0,0,0};

    if (fast) {
        // q1/qm panel only (offset KP); kh=0: steps 0..6, kh=1: steps 7..12
        const uint8_t* a0p = Acat + (size_t)(wm + r16) * KR + KP + ko;
        const uint8_t* a1p = a0p + 16 * KR;
        const uint8_t* b0p = Bcat + (size_t)(wn + r16) * KR + KP + ko;
        const uint8_t* b1p = b0p + 16 * KR;
        if (kh == 0) chain_i8<7, 0>(a0p, a1p, b0p, b1p, acc00, acc01, acc10, acc11);
        else         chain_i8<6, 7>(a0p, a1p, b0p, b1p, acc00, acc01, acc10, acc11);
    } else {
        const uint8_t* a0p = Acat + (size_t)(wm + r16) * KR + kh * KP + ko;
        const uint8_t* a1p = a0p + 16 * KR;
        const uint8_t* b0p = Bcat + (size_t)(wn + r16) * KR + kh * KP + ko;
        const uint8_t* b1p = b0p + 16 * KR;
        chain_i8<13, 0>(a0p, a1p, b0p, b1p, acc00, acc01, acc10, acc11);
    }

    // ---- combine: kh=1 writes to LDS; kh=0 dequants + t3 (+W fast), exp, stores ----
    __shared__ int red[2 * 32 * 33];         // 2 M-half slabs, padded stride 33
    const int hi4 = (lane >> 4) << 2;
    int* slab = red + qm * (32 * 33);
    if (kh) {
#define DUMP(ACC, MO, NO)                                             \
        { _Pragma("unroll")                                           \
          for (int qq = 0; qq < 4; ++qq)                              \
              slab[((MO) + hi4 + qq) * 33 + (NO) + r16] = ACC[qq]; }
        DUMP(acc00, 0, 0)  DUMP(acc01, 0, 16)
        DUMP(acc10, 16, 0) DUMP(acc11, 16, 16)
#undef DUMP
    }
    __syncthreads();
    if (!kh) {
        const int c0 = wn + r16, c1 = wn + 16 + r16;
        const float v0 = SV[c0], t0 = ST[c0];
        const float v1 = SV[c1], t1 = ST[c1];
        if (fast) {
            const float W0 = WR[c0], W1 = WR[c1];
#define FINF(ACC, MO, NO, VV, TT, WW)                                             \
        { const int rw0 = wm + (MO) + hi4;                                        \
          float* o_ = out + (size_t)rw0 * NR + wn + (NO) + r16;                   \
          _Pragma("unroll")                                                       \
          for (int qq = 0; qq < 4; ++qq) {                                        \
              const int rr = rw0 + qq;                                            \
              const int dq = ACC[qq] + slab[((MO) + hi4 + qq) * 33 + (NO) + r16]; \
              const float dist = (WW) + (TT) + SA1[rr] * (VV) * (float)dq;        \
              o_[qq * NR] = __expf(-0.5f * dist); } }
            FINF(acc00, 0, 0, v0, t0, W0)   FINF(acc01, 0, 16, v1, t1, W1)
            FINF(acc10, 16, 0, v0, t0, W0)  FINF(acc11, 16, 16, v1, t1, W1)
#undef FINF
        } else {
            const float u0 = SU[c0], u1 = SU[c1];
#define FIN(ACC, MO, NO, UU, VV, TT)                                              \
        { const int rw0 = wm + (MO) + hi4;                                        \
          float* o_ = out + (size_t)rw0 * NR + wn + (NO) + r16;                   \
          _Pragma("unroll")                                                       \
          for (int qq = 0; qq < 4; ++qq) {                                        \
              const int rr = rw0 + qq;                                            \
              const float d2 = (float)slab[((MO) + hi4 + qq) * 33 + (NO) + r16];  \
              const float dist = SA2[rr] * (UU) * (float)ACC[qq]                  \
                               + SA1[rr] * (VV) * d2 + (TT);                      \
              o_[qq * NR] = __expf(-0.5f * dist); } }
            FIN(acc00, 0, 0, u0, v0, t0)   FIN(acc01, 0, 16, u1, v1, t1)
            FIN(acc10, 16, 0, u0, v0, t0)  FIN(acc11, 16, 16, u1, v1, t1)
#undef FIN
        }
    }
}

extern "C" void kernel_launch(void* const* d_in, const int* in_sizes, int n_in,
                              void* d_out, int out_size, void* d_ws, size_t ws_size,
                              hipStream_t stream) {
    const float* inputs  = (const float*)d_in[0];
    const float* centers = (const float*)d_in[1];
    const float* sigmas  = (const float*)d_in[2];
    uint8_t* Acat = (uint8_t*)d_ws;                    // 2048*1664 = 3.41 MB
    uint8_t* Bcat = Acat + (size_t)NB * KR;            // + 256*1664 = 0.43 MB
    float*   scal = (float*)(Bcat + (size_t)NR * KR);  // + ~21 KB scales/flags
    float* SA1 = scal;                    // [2048]
    float* SA2 = scal + 2048;             // [2048]
    float* SU  = scal + 4096;             // [256]
    float* SV  = scal + 4352;             // [256]
    float* ST  = scal + 4608;             // [256]
    float* WR  = scal + 4864;             // [256]
    uint32_t* FLG = (uint32_t*)(scal + 5120);  // [256]
    prep_kernel<<<576, 256, 0, stream>>>(inputs, centers, sigmas, Acat, Bcat,
                                         SA1, SA2, SU, SV, ST, WR, FLG);
    rbf_gemm<<<256, 256, 0, stream>>>(Acat, Bcat, SA1, SA2, SU, SV, ST, WR, FLG,
                                      (float*)d_out);
}

// Round 10
// 15.339 us; speedup vs baseline: 2.3852x; 1.0320x over previous
//
#include <hip/hip_runtime.h>
#include <stdint.h>

// RBF layer: out[b,r] = exp(-0.5 * sum_d ((x[b,d]-c[r,d])^2 / s[r,d]^2)),
// x = l2_normalize(inputs).  INT8 GEMM with per-row max-scaling:
//   A_i8[b] = [ q2 = rint(x^2/s2_b) | q1 = rint(x/s1_b) ]          (2 panels x 832 B)
//   B_i8[r] = [ qw = rint(w/u_r)    | qm = rint(-2cw/v_r) ],  w = 1/s^2
//   dist = s2*u*dot(q2,qw) + s1*v*dot(q1,qm) + t3,   t3 = sum c^2 w  (f32 exact)
// Const-sigma fast path (R9): term1 = W_r exactly; only q1/qm panel needed.
// Model (9/9 fit): dur = C(~13us: replay + 2 launches + prep) + loaded_bytes/9.5TB/s.
// R10: dedup B inside gemm block via LDS staging (27.3 -> 20.5 MB loaded).

typedef int    i32x4 __attribute__((ext_vector_type(4)));
typedef float  f32x4 __attribute__((ext_vector_type(4)));

#define NB 2048
#define NR 256
#define ND 784
#define KR 1664   // row bytes: 2 panels x 832
#define KP 832    // panel: 784 data + 48 zero pad; 13 MFMA-K64 steps
#define PF 5
#define LB 848    // LDS B row stride (padded: 212 dwords -> 2-way bank alias, free)
#define INV127 0.007874015748031496f

// ---------------- prep: build int8 panels + per-row scales + const-sigma flags -------
__global__ __launch_bounds__(256) void prep_kernel(
        const float* __restrict__ inputs, const float* __restrict__ centers,
        const float* __restrict__ sigmas, uint8_t* __restrict__ Acat,
        uint8_t* __restrict__ Bcat, float* __restrict__ SA1, float* __restrict__ SA2,
        float* __restrict__ SU, float* __restrict__ SV, float* __restrict__ ST,
        float* __restrict__ WR, uint32_t* __restrict__ FLG)
{
    const int w    = threadIdx.x >> 6;
    const int lane = threadIdx.x & 63;
    const int blk  = blockIdx.x;
    if (blk < 512) {
        const int b = blk * 4 + w;
        const float4* src = (const float4*)(inputs + (size_t)b * ND);
        float4 v0 = src[lane];
        float4 v1 = src[lane + 64];
        float4 v2 = src[lane + 128];
        float4 v3 = make_float4(0.f, 0.f, 0.f, 0.f);
        if (lane < 4) v3 = src[lane + 192];            // 784 = 4*(64+64+64+4)
        float ss = v0.x*v0.x + v0.y*v0.y + v0.z*v0.z + v0.w*v0.w
                 + v1.x*v1.x + v1.y*v1.y + v1.z*v1.z + v1.w*v1.w
                 + v2.x*v2.x + v2.y*v2.y + v2.z*v2.z + v2.w*v2.w
                 + v3.x*v3.x + v3.y*v3.y + v3.z*v3.z + v3.w*v3.w;
        float mg = fmaxf(fmaxf(fmaxf(fabsf(v0.x), fabsf(v0.y)), fmaxf(fabsf(v0.z), fabsf(v0.w))),
                   fmaxf(fmaxf(fmaxf(fabsf(v1.x), fabsf(v1.y)), fmaxf(fabsf(v1.z), fabsf(v1.w))),
                   fmaxf(fmaxf(fmaxf(fabsf(v2.x), fabsf(v2.y)), fmaxf(fabsf(v2.z), fabsf(v2.w))),
                         fmaxf(fmaxf(fabsf(v3.x), fabsf(v3.y)), fmaxf(fabsf(v3.z), fabsf(v3.w))))));
        #pragma unroll
        for (int m = 32; m; m >>= 1) {
            ss += __shfl_xor(ss, m);
            mg  = fmaxf(mg, __shfl_xor(mg, m));
        }
        const float inv = rsqrtf(fmaxf(ss, 1e-12f));
        const float mx  = fmaxf(mg * inv, 1e-30f);     // max |x| over row
        const float r1  = 127.0f / mx;
        const float r2  = 127.0f / (mx * mx);
        uint8_t* rowA = Acat + (size_t)b * KR;
        auto pk = [&](float4 g, int col) {
            float x0 = g.x*inv, x1 = g.y*inv, x2 = g.z*inv, x3 = g.w*inv;
            int a0 = __float2int_rn(x0*x0*r2), a1 = __float2int_rn(x1*x1*r2);
            int a2 = __float2int_rn(x2*x2*r2), a3 = __float2int_rn(x3*x3*r2);
            int b0 = __float2int_rn(x0*r1),    b1 = __float2int_rn(x1*r1);
            int b2 = __float2int_rn(x2*r1),    b3 = __float2int_rn(x3*r1);
            uint32_t q2 = (a0&255) | ((a1&255)<<8) | ((a2&255)<<16) | ((a3&255)<<24);
            uint32_t q1 = (b0&255) | ((b1&255)<<8) | ((b2&255)<<16) | ((b3&255)<<24);
            *(uint32_t*)(rowA + col)      = q2;
            *(uint32_t*)(rowA + KP + col) = q1;
        };
        pk(v0, 4*lane);
        pk(v1, 4*(lane+64));
        pk(v2, 4*(lane+128));
        if (lane < 4) pk(v3, 4*(lane+192));
        if (lane < 12) {                               // zero pad cols [784,832) both panels
            *(uint32_t*)(rowA + ND + 4*lane)      = 0u;
            *(uint32_t*)(rowA + KP + ND + 4*lane) = 0u;
        }
        if (lane == 0) { SA1[b] = mx * INV127; SA2[b] = mx * mx * INV127; }
    } else {
        const int r = (blk - 512) * 4 + w;
        const float4* cp = (const float4*)(centers + (size_t)r * ND);
        const float4* sp = (const float4*)(sigmas  + (size_t)r * ND);
        float4 c0 = cp[lane],     s0 = sp[lane];
        float4 c1 = cp[lane+64],  s1 = sp[lane+64];
        float4 c2 = cp[lane+128], s2 = sp[lane+128];
        float4 c3 = make_float4(0,0,0,0), s3 = make_float4(1,1,1,1);
        const bool v3ok = lane < 4;
        if (v3ok) { c3 = cp[lane+192]; s3 = sp[lane+192]; }
        float4 w0, w1, w2, w3;
        w0.x=1.f/(s0.x*s0.x); w0.y=1.f/(s0.y*s0.y); w0.z=1.f/(s0.z*s0.z); w0.w=1.f/(s0.w*s0.w);
        w1.x=1.f/(s1.x*s1.x); w1.y=1.f/(s1.y*s1.y); w1.z=1.f/(s1.z*s1.z); w1.w=1.f/(s1.w*s1.w);
        w2.x=1.f/(s2.x*s2.x); w2.y=1.f/(s2.y*s2.y); w2.z=1.f/(s2.z*s2.z); w2.w=1.f/(s2.w*s2.w);
        w3.x=1.f/(s3.x*s3.x); w3.y=1.f/(s3.y*s3.y); w3.z=1.f/(s3.z*s3.z); w3.w=1.f/(s3.w*s3.w);
        // row-constancy: min/max over REAL elements only
        float wmn = fminf(fminf(fminf(w0.x,w0.y), fminf(w0.z,w0.w)),
                    fminf(fminf(fminf(w1.x,w1.y), fminf(w1.z,w1.w)),
                          fminf(fminf(w2.x,w2.y), fminf(w2.z,w2.w))));
        float wmx = fmaxf(fmaxf(fmaxf(w0.x,w0.y), fmaxf(w0.z,w0.w)),
                    fmaxf(fmaxf(fmaxf(w1.x,w1.y), fmaxf(w1.z,w1.w)),
                          fmaxf(fmaxf(w2.x,w2.y), fmaxf(w2.z,w2.w))));
        if (v3ok) {
            wmn = fminf(wmn, fminf(fminf(w3.x,w3.y), fminf(w3.z,w3.w)));
            wmx = fmaxf(wmx, fmaxf(fmaxf(w3.x,w3.y), fmaxf(w3.z,w3.w)));
        }
        if (!v3ok) { w3 = make_float4(0,0,0,0); }      // neutral for t3 / mm sums below
        float t3 = c0.x*c0.x*w0.x + c0.y*c0.y*w0.y + c0.z*c0.z*w0.z + c0.w*c0.w*w0.w
                 + c1.x*c1.x*w1.x + c1.y*c1.y*w1.y + c1.z*c1.z*w1.z + c1.w*c1.w*w1.w
                 + c2.x*c2.x*w2.x + c2.y*c2.y*w2.y + c2.z*c2.z*w2.z + c2.w*c2.w*w2.w
                 + c3.x*c3.x*w3.x + c3.y*c3.y*w3.y + c3.z*c3.z*w3.z + c3.w*c3.w*w3.w;
        float mw = fmaxf(fmaxf(w0.x, w0.y), fmaxf(w0.z, w0.w));
        mw = fmaxf(mw, fmaxf(fmaxf(w1.x, w1.y), fmaxf(w1.z, w1.w)));
        mw = fmaxf(mw, fmaxf(fmaxf(w2.x, w2.y), fmaxf(w2.z, w2.w)));
        mw = fmaxf(mw, fmaxf(fmaxf(w3.x, w3.y), fmaxf(w3.z, w3.w)));
        float mm = fmaxf(fmaxf(fabsf(2.f*c0.x*w0.x), fabsf(2.f*c0.y*w0.y)),
                         fmaxf(fabsf(2.f*c0.z*w0.z), fabsf(2.f*c0.w*w0.w)));
        mm = fmaxf(mm, fmaxf(fmaxf(fabsf(2.f*c1.x*w1.x), fabsf(2.f*c1.y*w1.y)),
                             fmaxf(fabsf(2.f*c1.z*w1.z), fabsf(2.f*c1.w*w1.w))));
        mm = fmaxf(mm, fmaxf(fmaxf(fabsf(2.f*c2.x*w2.x), fabsf(2.f*c2.y*w2.y)),
                             fmaxf(fabsf(2.f*c2.z*w2.z), fabsf(2.f*c2.w*w2.w))));
        mm = fmaxf(mm, fmaxf(fmaxf(fabsf(2.f*c3.x*w3.x), fabsf(2.f*c3.y*w3.y)),
                             fmaxf(fabsf(2.f*c3.z*w3.z), fabsf(2.f*c3.w*w3.w))));
        #pragma unroll
        for (int m = 32; m; m >>= 1) {
            t3 += __shfl_xor(t3, m);
            mw  = fmaxf(mw, __shfl_xor(mw, m));
            mm  = fmaxf(mm, __shfl_xor(mm, m));
            wmn = fminf(wmn, __shfl_xor(wmn, m));
            wmx = fmaxf(wmx, __shfl_xor(wmx, m));
        }
        mw = fmaxf(mw, 1e-30f); mm = fmaxf(mm, 1e-30f);
        const float ru = 127.0f / mw, rv = 127.0f / mm;
        uint8_t* rowB = Bcat + (size_t)r * KR;
        auto pkB = [&](float4 c, float4 ww, int col) {
            int a0 = __float2int_rn(ww.x*ru), a1 = __float2int_rn(ww.y*ru);
            int a2 = __float2int_rn(ww.z*ru), a3 = __float2int_rn(ww.w*ru);
            int b0 = __float2int_rn(-2.f*c.x*ww.x*rv), b1 = __float2int_rn(-2.f*c.y*ww.y*rv);
            int b2 = __float2int_rn(-2.f*c.z*ww.z*rv), b3 = __float2int_rn(-2.f*c.w*ww.w*rv);
            uint32_t qw = (a0&255) | ((a1&255)<<8) | ((a2&255)<<16) | ((a3&255)<<24);
            uint32_t qm = (b0&255) | ((b1&255)<<8) | ((b2&255)<<16) | ((b3&255)<<24);
            *(uint32_t*)(rowB + col)      = qw;
            *(uint32_t*)(rowB + KP + col) = qm;
        };
        pkB(c0, w0, 4*lane);
        pkB(c1, w1, 4*(lane+64));
        pkB(c2, w2, 4*(lane+128));
        if (v3ok) pkB(c3, w3, 4*(lane+192));
        if (lane < 12) {
            *(uint32_t*)(rowB + ND + 4*lane)      = 0u;
            *(uint32_t*)(rowB + KP + ND + 4*lane) = 0u;
        }
        if (lane == 0) {
            SU[r] = mw * INV127; SV[r] = mm * INV127; ST[r] = t3;
            WR[r] = wmn; FLG[r] = (wmn == wmx) ? 1u : 0u;
        }
    }
}

// ---- K-chain (global B): NST steps of K=64 from step BASE; PF pipeline ----
#define LDSET(J, KS) do { const int o_ = (KS) * 64;                           \
    a0[J] = *(const i32x4*)(a0p + o_); a1[J] = *(const i32x4*)(a1p + o_);     \
    b0[J] = *(const i32x4*)(b0p + o_); b1[J] = *(const i32x4*)(b1p + o_); } while (0)
#define MM(J) do {                                                                 \
    acc00 = __builtin_amdgcn_mfma_i32_16x16x64_i8(a0[J], b0[J], acc00, 0, 0, 0);   \
    acc01 = __builtin_amdgcn_mfma_i32_16x16x64_i8(a0[J], b1[J], acc01, 0, 0, 0);   \
    acc10 = __builtin_amdgcn_mfma_i32_16x16x64_i8(a1[J], b0[J], acc10, 0, 0, 0);   \
    acc11 = __builtin_amdgcn_mfma_i32_16x16x64_i8(a1[J], b1[J], acc11, 0, 0, 0); } while (0)

template<int NST, int BASE>
__device__ __forceinline__ void chain_i8(
        const uint8_t* __restrict__ a0p, const uint8_t* __restrict__ a1p,
        const uint8_t* __restrict__ b0p, const uint8_t* __restrict__ b1p,
        i32x4& acc00, i32x4& acc01, i32x4& acc10, i32x4& acc11)
{
    i32x4 a0[PF], a1[PF], b0[PF], b1[PF];
    constexpr int PRE = (PF < NST) ? PF : NST;
    #pragma unroll
    for (int s = 0; s < PRE; ++s) LDSET(s, BASE + s);
    #pragma unroll
    for (int s = 0; s < NST; ++s) {
        MM(s % PF);
        if (s + PF < NST) LDSET(s % PF, BASE + s + PF);
    }
}
#undef LDSET

// ---- K-chain (LDS B): A from global, B fragments via ds_read_b128 ----
#define LDSETF(J, KS) do { const int o_ = (KS) * 64;                            \
    a0[J] = *(const i32x4*)(a0p + o_); a1[J] = *(const i32x4*)(a1p + o_);       \
    b0[J] = *(const i32x4*)(ldsB0 + o_); b1[J] = *(const i32x4*)(ldsB1 + o_); } while (0)

template<int NST, int BASE>
__device__ __forceinline__ void chain_ldsb(
        const uint8_t* __restrict__ a0p, const uint8_t* __restrict__ a1p,
        const uint8_t* ldsB0, const uint8_t* ldsB1,
        i32x4& acc00, i32x4& acc01, i32x4& acc10, i32x4& acc11)
{
    i32x4 a0[PF], a1[PF], b0[PF], b1[PF];
    constexpr int PRE = (PF < NST) ? PF : NST;
    #pragma unroll
    for (int s = 0; s < PRE; ++s) LDSETF(s, BASE + s);
    #pragma unroll
    for (int s = 0; s < NST; ++s) {
        MM(s % PF);
        if (s + PF < NST) LDSETF(s % PF, BASE + s + PF);
    }
}
#undef LDSETF
#undef MM

// ---------------- GEMM: 256 blocks x 4 waves; 64x32 tile ----------------
// Fast path: B q1-panel staged once in LDS (dedups the 2x qm-pair load), K-split 7/6
// across kh.  Slow path: R8 two-panel global split.  kh=1 dumps acc to LDS; kh=0
// combines + exp + stores.
__global__ __launch_bounds__(256) void rbf_gemm(
        const uint8_t* __restrict__ Acat, const uint8_t* __restrict__ Bcat,
        const float* __restrict__ SA1, const float* __restrict__ SA2,
        const float* __restrict__ SU, const float* __restrict__ SV,
        const float* __restrict__ ST, const float* __restrict__ WR,
        const uint32_t* __restrict__ FLG, float* __restrict__ out)
{
    const int w    = threadIdx.x >> 6;   // 0..3
    const int lane = threadIdx.x & 63;
    const int bid  = (int)blockIdx.x;
    const int xcd  = bid & 7;
    const int j    = bid >> 3;           // 0..31
    const int mt   = xcd * 4 + (j & 3);  // 0..31
    const int nt   = j >> 2;             // 0..7
    const int qm   = w >> 1;             // M half
    const int kh   = w & 1;              // panel (slow) / K-chunk (fast)
    const int wm   = mt * 64 + qm * 32;
    const int wn   = nt * 32;
    const int r16  = lane & 15;
    const int ko   = (lane >> 4) * 16;   // byte offset within K=64 step

    __shared__ uint8_t ldsB[32 * LB];    // 27.1 KB staged B q1-panel
    __shared__ int     red[2 * 32 * 33]; // 8.4 KB reduce slabs

    uint32_t fv = 1u;
    if (lane < 32) fv = FLG[wn + lane];
    const bool fast = __all(fv != 0u);   // block-uniform (wn same for all waves)

    i32x4 acc00 = {0,0,0,0}, acc01 = {0,0,0,0}, acc10 = {0,0,0,0}, acc11 = {0,0,0,0};

    if (fast) {
        // ---- stage B q1-panel to LDS: 32 rows x 832 B, 8 threads/row x 16 B ----
        {
            const int sr = (int)threadIdx.x >> 3;         // 0..31
            const int sc = ((int)threadIdx.x & 7) * 16;   // 0,16,..,112
            const uint8_t* gsrc = Bcat + (size_t)(wn + sr) * KR + KP;
            #pragma unroll
            for (int p = 0; p < 7; ++p) {
                const int col = p * 128 + sc;
                if (col < KP)
                    *(i32x4*)(ldsB + sr * LB + col) = *(const i32x4*)(gsrc + col);
            }
        }
        __syncthreads();                  // uniform branch: all waves take fast path
        const uint8_t* a0p = Acat + (size_t)(wm + r16) * KR + KP + ko;
        const uint8_t* a1p = a0p + 16 * KR;
        const uint8_t* ldsB0 = ldsB + r16 * LB + ko;
        const uint8_t* ldsB1 = ldsB0 + 16 * LB;
        if (kh == 0) chain_ldsb<7, 0>(a0p, a1p, ldsB0, ldsB1, acc00, acc01, acc10, acc11);
        else         chain_ldsb<6, 7>(a0p, a1p, ldsB0, ldsB1, acc00, acc01, acc10, acc11);
    } else {
        const uint8_t* a0p = Acat + (size_t)(wm + r16) * KR + kh * KP + ko;
        const uint8_t* a1p = a0p + 16 * KR;
        const uint8_t* b0p = Bcat + (size_t)(wn + r16) * KR + kh * KP + ko;
        const uint8_t* b1p = b0p + 16 * KR;
        chain_i8<13, 0>(a0p, a1p, b0p, b1p, acc00, acc01, acc10, acc11);
    }

    // ---- combine: kh=1 writes to LDS; kh=0 dequants + t3 (+W fast), exp, stores ----
    const int hi4 = (lane >> 4) << 2;
    int* slab = red + qm * (32 * 33);
    if (kh) {
#define DUMP(ACC, MO, NO)                                             \
        { _Pragma("unroll")                                           \
          for (int qq = 0; qq < 4; ++qq)                              \
              slab[((MO) + hi4 + qq) * 33 + (NO) + r16] = ACC[qq]; }
        DUMP(acc00, 0, 0)  DUMP(acc01, 0, 16)
        DUMP(acc10, 16, 0) DUMP(acc11, 16, 16)
#undef DUMP
    }
    __syncthreads();
    if (!kh) {
        const int c0 = wn + r16, c1 = wn + 16 + r16;
        const float v0 = SV[c0], t0 = ST[c0];
        const float v1 = SV[c1], t1 = ST[c1];
        if (fast) {
            const float W0 = WR[c0], W1 = WR[c1];
#define FINF(ACC, MO, NO, VV, TT, WW)                                             \
        { const int rw0 = wm + (MO) + hi4;                                        \
          float* o_ = out + (size_t)rw0 * NR + wn + (NO) + r16;                   \
          _Pragma("unroll")                                                       \
          for (int qq = 0; qq < 4; ++qq) {                                        \
              const int rr = rw0 + qq;                                            \
              const int dq = ACC[qq] + slab[((MO) + hi4 + qq) * 33 + (NO) + r16]; \
              const float dist = (WW) + (TT) + SA1[rr] * (VV) * (float)dq;        \
              o_[qq * NR] = __expf(-0.5f * dist); } }
            FINF(acc00, 0, 0, v0, t0, W0)   FINF(acc01, 0, 16, v1, t1, W1)
            FINF(acc10, 16, 0, v0, t0, W0)  FINF(acc11, 16, 16, v1, t1, W1)
#undef FINF
        } else {
            const float u0 = SU[c0], u1 = SU[c1];
#define FIN(ACC, MO, NO, UU, VV, TT)                                              \
        { const int rw0 = wm + (MO) + hi4;                                        \
          float* o_ = out + (size_t)rw0 * NR + wn + (NO) + r16;                   \
          _Pragma("unroll")                                                       \
          for (int qq = 0; qq < 4; ++qq) {                                        \
              const int rr = rw0 + qq;                                            \
              const float d2 = (float)slab[((MO) + hi4 + qq) * 33 + (NO) + r16];  \
              const float dist = SA2[rr] * (UU) * (float)ACC[qq]                  \
                               + SA1[rr] * (VV) * d2 + (TT);                      \
              o_[qq * NR] = __expf(-0.5f * dist); } }
            FIN(acc00, 0, 0, u0, v0, t0)   FIN(acc01, 0, 16, u1, v1, t1)
            FIN(acc10, 16, 0, u0, v0, t0)  FIN(acc11, 16, 16, u1, v1, t1)
#undef FIN
        }
    }
}

extern "C" void kernel_launch(void* const* d_in, const int* in_sizes, int n_in,
                              void* d_out, int out_size, void* d_ws, size_t ws_size,
                              hipStream_t stream) {
    const float* inputs  = (const float*)d_in[0];
    const float* centers = (const float*)d_in[1];
    const float* sigmas  = (const float*)d_in[2];
    uint8_t* Acat = (uint8_t*)d_ws;                    // 2048*1664 = 3.41 MB
    uint8_t* Bcat = Acat + (size_t)NB * KR;            // + 256*1664 = 0.43 MB
    float*   scal = (float*)(Bcat + (size_t)NR * KR);  // + ~21 KB scales/flags
    float* SA1 = scal;                    // [2048]
    float* SA2 = scal + 2048;             // [2048]
    float* SU  = scal + 4096;             // [256]
    float* SV  = scal + 4352;             // [256]
    float* ST  = scal + 4608;             // [256]
    float* WR  = scal + 4864;             // [256]
    uint32_t* FLG = (uint32_t*)(scal + 5120);  // [256]
    prep_kernel<<<576, 256, 0, stream>>>(inputs, centers, sigmas, Acat, Bcat,
                                         SA1, SA2, SU, SV, ST, WR, FLG);
    rbf_gemm<<<256, 256, 0, stream>>>(Acat, Bcat, SA1, SA2, SU, SV, ST, WR, FLG,
                                      (float*)d_out);
}